// Round 1
// baseline (569.944 us; speedup 1.0000x reference)
//
#include <hip/hip_runtime.h>
#include <hip/hip_bf16.h>

#define NN 50000
#define EE 600000
#define DD 128
#define LL 3
#define LN_EPS 1e-5f

// ---------------- CSR build ----------------

__global__ void degree_kernel(const int* __restrict__ dst, int* __restrict__ deg) {
    int i = blockIdx.x * blockDim.x + threadIdx.x;
    if (i < EE) atomicAdd(&deg[dst[i]], 1);
}

__global__ void dinv_kernel(const int* __restrict__ deg, float* __restrict__ dinv) {
    int i = blockIdx.x * blockDim.x + threadIdx.x;
    if (i < NN) dinv[i] = rsqrtf((float)(deg[i] + 1));  // +1 self-loop
}

// single-block exclusive scan of (deg[i]+1) -> rowoff[0..N], rowoff[N]=total
__global__ __launch_bounds__(1024) void scan_kernel(const int* __restrict__ deg,
                                                    int* __restrict__ rowoff) {
    __shared__ int sums[1024];
    int tid = threadIdx.x;
    const int chunk = (NN + 1023) / 1024;  // 49
    int begin = tid * chunk;
    int end = begin + chunk; if (end > NN) end = NN;
    int s = 0;
    for (int i = begin; i < end; i++) s += deg[i] + 1;
    sums[tid] = s;
    __syncthreads();
    for (int off = 1; off < 1024; off <<= 1) {
        int v = sums[tid];
        int add = (tid >= off) ? sums[tid - off] : 0;
        __syncthreads();
        sums[tid] = v + add;
        __syncthreads();
    }
    int prefix = (tid == 0) ? 0 : sums[tid - 1];
    int run = prefix;
    for (int i = begin; i < end; i++) { rowoff[i] = run; run += deg[i] + 1; }
    if (tid == 1023) rowoff[NN] = sums[1023];
}

__global__ void fill_kernel(const int* __restrict__ src, const int* __restrict__ dst,
                            const float* __restrict__ dinv, int* __restrict__ cursor,
                            int* __restrict__ csrc, float* __restrict__ cnorm) {
    int i = blockIdx.x * blockDim.x + threadIdx.x;
    if (i >= EE + NN) return;
    int s, d;
    if (i < EE) { s = src[i]; d = dst[i]; }
    else        { s = i - EE; d = s; }
    int pos = atomicAdd(&cursor[d], 1);
    csrc[pos] = s;
    cnorm[pos] = dinv[s] * dinv[d];
}

// ---------------- GEMM: C[N,128] = A[N,128] @ W[128,128] ----------------
// 64x128 tile per block, 256 threads, 4x8 per thread.

#define BM 64
#define BN 128
#define BK 16

__global__ __launch_bounds__(256) void gemm_kernel(const float* __restrict__ A,
                                                   const float* __restrict__ W,
                                                   float* __restrict__ C) {
    __shared__ float As[BK][BM + 4];   // transposed A tile, pad 4 keeps 16B align
    __shared__ float Bs[BK][BN + 4];
    int tid = threadIdx.x;
    int tx = tid & 15;    // col group: 8 cols
    int ty = tid >> 4;    // row group: 4 rows
    int rowbase = blockIdx.x * BM;
    float acc[4][8] = {};

    for (int k0 = 0; k0 < DD; k0 += BK) {
        // A tile: 64 rows x 16 k (each thread one float4 along k, store transposed)
        {
            int r = tid >> 2;
            int kq = (tid & 3) * 4;
            int grow = rowbase + r;
            float4 av = make_float4(0.f, 0.f, 0.f, 0.f);
            if (grow < NN) av = *(const float4*)&A[grow * DD + k0 + kq];
            As[kq + 0][r] = av.x; As[kq + 1][r] = av.y;
            As[kq + 2][r] = av.z; As[kq + 3][r] = av.w;
        }
        // B tile: 16 k x 128 cols (each thread two float4, coalesced)
        {
            int kk = tid >> 4;          // 0..15
            int col = (tid & 15) * 8;   // 0..120
            const float* wp = &W[(k0 + kk) * DD + col];
            *(float4*)&Bs[kk][col]     = *(const float4*)&wp[0];
            *(float4*)&Bs[kk][col + 4] = *(const float4*)&wp[4];
        }
        __syncthreads();
        #pragma unroll
        for (int kk = 0; kk < BK; kk++) {
            float4 a  = *(const float4*)&As[kk][ty * 4];
            float4 b0 = *(const float4*)&Bs[kk][tx * 8];
            float4 b1 = *(const float4*)&Bs[kk][tx * 8 + 4];
            float av[4] = {a.x, a.y, a.z, a.w};
            float bv[8] = {b0.x, b0.y, b0.z, b0.w, b1.x, b1.y, b1.z, b1.w};
            #pragma unroll
            for (int i = 0; i < 4; i++)
                #pragma unroll
                for (int j = 0; j < 8; j++)
                    acc[i][j] += av[i] * bv[j];
        }
        __syncthreads();
    }
    #pragma unroll
    for (int i = 0; i < 4; i++) {
        int grow = rowbase + ty * 4 + i;
        if (grow < NN) {
            *(float4*)&C[grow * DD + tx * 8]     = make_float4(acc[i][0], acc[i][1], acc[i][2], acc[i][3]);
            *(float4*)&C[grow * DD + tx * 8 + 4] = make_float4(acc[i][4], acc[i][5], acc[i][6], acc[i][7]);
        }
    }
}

// ---------------- fused aggregate + bias + LayerNorm + PReLU ----------------
// one block (128 threads = 2 waves) per node; thread t owns feature t.

__global__ __launch_bounds__(128) void agg_ln_kernel(
    const float* __restrict__ T, const int* __restrict__ rowoff,
    const int* __restrict__ csrc, const float* __restrict__ cnorm,
    const float* __restrict__ bias, const float* __restrict__ lnw,
    const float* __restrict__ lnb, const float* __restrict__ alphas, int layer,
    float* __restrict__ out) {
    int node = blockIdx.x;
    int tid = threadIdx.x;
    int start = rowoff[node];
    int end = rowoff[node + 1];

    float acc = 0.f;
    for (int e = start; e < end; e++) {
        int s = csrc[e];
        float w = cnorm[e];
        acc += T[s * DD + tid] * w;
    }
    acc += bias[tid];

    // block reduce sum / sumsq over 128 lanes (2 waves)
    float s1 = acc, s2 = acc * acc;
    #pragma unroll
    for (int off = 32; off > 0; off >>= 1) {
        s1 += __shfl_down(s1, off);
        s2 += __shfl_down(s2, off);
    }
    __shared__ float red[4];
    int wave = tid >> 6;
    if ((tid & 63) == 0) { red[wave * 2] = s1; red[wave * 2 + 1] = s2; }
    __syncthreads();
    float sum = red[0] + red[2];
    float sumsq = red[1] + red[3];
    float mu = sum * (1.f / DD);
    float var = sumsq * (1.f / DD) - mu * mu;
    float rstd = rsqrtf(var + LN_EPS);
    float y = (acc - mu) * rstd * lnw[tid] + lnb[tid];
    float alpha = alphas[layer];
    y = (y >= 0.f) ? y : alpha * y;
    out[node * DD + tid] = y;
}

// ---------------- launch ----------------

extern "C" void kernel_launch(void* const* d_in, const int* in_sizes, int n_in,
                              void* d_out, int out_size, void* d_ws, size_t ws_size,
                              hipStream_t stream) {
    const float* x    = (const float*)d_in[0];
    const int*   ei   = (const int*)d_in[1];
    const float* Ws   = (const float*)d_in[2];
    const float* bs   = (const float*)d_in[3];
    const float* lnw  = (const float*)d_in[4];
    const float* lnb  = (const float*)d_in[5];
    const float* alphas = (const float*)d_in[6];
    float* out = (float*)d_out;

    const int* src = ei;
    const int* dst = ei + EE;

    char* ws = (char*)d_ws;
    size_t off = 0;
    auto alloc = [&](size_t bytes) -> void* {
        void* p = ws + off;
        off = (off + bytes + 255) & ~(size_t)255;
        return p;
    };
    int*   deg    = (int*)alloc(NN * sizeof(int));
    float* dinv   = (float*)alloc(NN * sizeof(float));
    int*   rowoff = (int*)alloc((NN + 1) * sizeof(int));
    int*   cursor = (int*)alloc(NN * sizeof(int));
    int*   csrc   = (int*)alloc((size_t)(EE + NN) * sizeof(int));
    float* cnorm  = (float*)alloc((size_t)(EE + NN) * sizeof(float));
    float* tbuf   = (float*)alloc((size_t)NN * DD * sizeof(float));
    float* hbuf   = (float*)alloc((size_t)NN * DD * sizeof(float));

    hipMemsetAsync(deg, 0, NN * sizeof(int), stream);
    degree_kernel<<<(EE + 255) / 256, 256, 0, stream>>>(dst, deg);
    dinv_kernel<<<(NN + 255) / 256, 256, 0, stream>>>(deg, dinv);
    scan_kernel<<<1, 1024, 0, stream>>>(deg, rowoff);
    hipMemcpyAsync(cursor, rowoff, NN * sizeof(int), hipMemcpyDeviceToDevice, stream);
    fill_kernel<<<(EE + NN + 255) / 256, 256, 0, stream>>>(src, dst, dinv, cursor, csrc, cnorm);

    const int gemm_grid = (NN + BM - 1) / BM;
    for (int l = 0; l < LL; l++) {
        const float* A = (l == 0) ? x : hbuf;
        float* O = (l == LL - 1) ? out : hbuf;
        gemm_kernel<<<gemm_grid, 256, 0, stream>>>(A, Ws + (size_t)l * DD * DD, tbuf);
        agg_ln_kernel<<<NN, DD, 0, stream>>>(tbuf, rowoff, csrc, cnorm,
                                             bs + l * DD, lnw + l * DD, lnb + l * DD,
                                             alphas, l, O);
    }
}

// Round 2
// 403.408 us; speedup vs baseline: 1.4128x; 1.4128x over previous
//
#include <hip/hip_runtime.h>
#include <hip/hip_bf16.h>

#define NN 50000
#define EE 600000
#define DD 128
#define LL 3
#define LN_EPS 1e-5f

// ---------------- CSR build ----------------

__global__ void degree_kernel(const int* __restrict__ dst, int* __restrict__ deg) {
    int i = blockIdx.x * blockDim.x + threadIdx.x;
    if (i < EE) atomicAdd(&deg[dst[i]], 1);
}

__global__ void dinv_kernel(const int* __restrict__ deg, float* __restrict__ dinv) {
    int i = blockIdx.x * blockDim.x + threadIdx.x;
    if (i < NN) dinv[i] = rsqrtf((float)(deg[i] + 1));  // +1 self-loop
}

// ---- hierarchical exclusive scan of (deg[i]+1) -> rowoff[0..N] ----
#define SCAN_NB ((NN + 255) / 256)   // 196

__global__ __launch_bounds__(256) void scan1_kernel(const int* __restrict__ deg,
                                                    int* __restrict__ blocksum) {
    __shared__ int red[4];
    int i = blockIdx.x * 256 + threadIdx.x;
    int v = (i < NN) ? (deg[i] + 1) : 0;
    // wave reduce (64) then across 4 waves
    int s = v;
    #pragma unroll
    for (int off = 32; off > 0; off >>= 1) s += __shfl_down(s, off);
    if ((threadIdx.x & 63) == 0) red[threadIdx.x >> 6] = s;
    __syncthreads();
    if (threadIdx.x == 0) blocksum[blockIdx.x] = red[0] + red[1] + red[2] + red[3];
}

__global__ __launch_bounds__(256) void scan2_kernel(const int* __restrict__ blocksum,
                                                    int* __restrict__ blockpre,
                                                    int* __restrict__ rowoff) {
    __shared__ int s[256];
    int t = threadIdx.x;
    int v = (t < SCAN_NB) ? blocksum[t] : 0;
    s[t] = v;
    __syncthreads();
    #pragma unroll
    for (int off = 1; off < 256; off <<= 1) {
        int add = (t >= off) ? s[t - off] : 0;
        __syncthreads();
        s[t] += add;
        __syncthreads();
    }
    if (t < SCAN_NB) blockpre[t] = s[t] - v;  // exclusive
    if (t == 255) rowoff[NN] = s[255];        // grand total
}

__global__ __launch_bounds__(256) void scan3_kernel(const int* __restrict__ deg,
                                                    const int* __restrict__ blockpre,
                                                    int* __restrict__ rowoff) {
    __shared__ int s[256];
    int t = threadIdx.x;
    int i = blockIdx.x * 256 + t;
    int v = (i < NN) ? (deg[i] + 1) : 0;
    s[t] = v;
    __syncthreads();
    #pragma unroll
    for (int off = 1; off < 256; off <<= 1) {
        int add = (t >= off) ? s[t - off] : 0;
        __syncthreads();
        s[t] += add;
        __syncthreads();
    }
    if (i < NN) rowoff[i] = blockpre[blockIdx.x] + s[t] - v;
}

__global__ void fill_kernel(const int* __restrict__ src, const int* __restrict__ dst,
                            const float* __restrict__ dinv, int* __restrict__ cursor,
                            int* __restrict__ csrc, float* __restrict__ cnorm) {
    int i = blockIdx.x * blockDim.x + threadIdx.x;
    if (i >= EE + NN) return;
    int s, d;
    if (i < EE) { s = src[i]; d = dst[i]; }
    else        { s = i - EE; d = s; }
    int pos = atomicAdd(&cursor[d], 1);
    csrc[pos] = s;
    cnorm[pos] = dinv[s] * dinv[d];
}

// ---------------- GEMM: C[N,128] = A[N,128] @ W[128,128] ----------------
// 64x128 tile per block, 256 threads, 4x8 per thread.

#define BM 64
#define BN 128
#define BK 16

__global__ __launch_bounds__(256) void gemm_kernel(const float* __restrict__ A,
                                                   const float* __restrict__ W,
                                                   float* __restrict__ C) {
    __shared__ float As[BK][BM + 4];
    __shared__ float Bs[BK][BN + 4];
    int tid = threadIdx.x;
    int tx = tid & 15;    // col group: 8 cols
    int ty = tid >> 4;    // row group: 4 rows
    int rowbase = blockIdx.x * BM;
    float acc[4][8] = {};

    for (int k0 = 0; k0 < DD; k0 += BK) {
        {
            int r = tid >> 2;
            int kq = (tid & 3) * 4;
            int grow = rowbase + r;
            float4 av = make_float4(0.f, 0.f, 0.f, 0.f);
            if (grow < NN) av = *(const float4*)&A[grow * DD + k0 + kq];
            As[kq + 0][r] = av.x; As[kq + 1][r] = av.y;
            As[kq + 2][r] = av.z; As[kq + 3][r] = av.w;
        }
        {
            int kk = tid >> 4;
            int col = (tid & 15) * 8;
            const float* wp = &W[(k0 + kk) * DD + col];
            *(float4*)&Bs[kk][col]     = *(const float4*)&wp[0];
            *(float4*)&Bs[kk][col + 4] = *(const float4*)&wp[4];
        }
        __syncthreads();
        #pragma unroll
        for (int kk = 0; kk < BK; kk++) {
            float4 a  = *(const float4*)&As[kk][ty * 4];
            float4 b0 = *(const float4*)&Bs[kk][tx * 8];
            float4 b1 = *(const float4*)&Bs[kk][tx * 8 + 4];
            float av[4] = {a.x, a.y, a.z, a.w};
            float bv[8] = {b0.x, b0.y, b0.z, b0.w, b1.x, b1.y, b1.z, b1.w};
            #pragma unroll
            for (int i = 0; i < 4; i++)
                #pragma unroll
                for (int j = 0; j < 8; j++)
                    acc[i][j] += av[i] * bv[j];
        }
        __syncthreads();
    }
    #pragma unroll
    for (int i = 0; i < 4; i++) {
        int grow = rowbase + ty * 4 + i;
        if (grow < NN) {
            *(float4*)&C[grow * DD + tx * 8]     = make_float4(acc[i][0], acc[i][1], acc[i][2], acc[i][3]);
            *(float4*)&C[grow * DD + tx * 8 + 4] = make_float4(acc[i][4], acc[i][5], acc[i][6], acc[i][7]);
        }
    }
}

// ---------------- fused aggregate + bias + LayerNorm + PReLU ----------------
// 128 threads/block = 4 groups of 32 lanes; group g handles node blockIdx*4+g.
// Lane l owns features [4l, 4l+4) as a float4. No LDS, no __syncthreads.

__global__ __launch_bounds__(128) void agg_ln_kernel(
    const float* __restrict__ T, const int* __restrict__ rowoff,
    const int* __restrict__ csrc, const float* __restrict__ cnorm,
    const float* __restrict__ bias, const float* __restrict__ lnw,
    const float* __restrict__ lnb, const float* __restrict__ alphas, int layer,
    float* __restrict__ out) {
    int g = threadIdx.x >> 5;
    int lane = threadIdx.x & 31;
    int node = blockIdx.x * 4 + g;
    if (node >= NN) return;
    int start = rowoff[node];
    int end = rowoff[node + 1];
    int f4 = lane * 4;

    float ax = 0.f, ay = 0.f, az = 0.f, aw = 0.f;
    int e = start;
    for (; e + 1 < end; e += 2) {
        int s0 = csrc[e];
        int s1 = csrc[e + 1];
        float w0 = cnorm[e];
        float w1 = cnorm[e + 1];
        float4 v0 = *(const float4*)&T[(size_t)s0 * DD + f4];
        float4 v1 = *(const float4*)&T[(size_t)s1 * DD + f4];
        ax += w0 * v0.x + w1 * v1.x;
        ay += w0 * v0.y + w1 * v1.y;
        az += w0 * v0.z + w1 * v1.z;
        aw += w0 * v0.w + w1 * v1.w;
    }
    if (e < end) {
        int s0 = csrc[e];
        float w0 = cnorm[e];
        float4 v0 = *(const float4*)&T[(size_t)s0 * DD + f4];
        ax += w0 * v0.x; ay += w0 * v0.y; az += w0 * v0.z; aw += w0 * v0.w;
    }
    float4 b4 = *(const float4*)&bias[f4];
    ax += b4.x; ay += b4.y; az += b4.z; aw += b4.w;

    float s1 = ax + ay + az + aw;
    float s2 = ax * ax + ay * ay + az * az + aw * aw;
    #pragma unroll
    for (int off = 16; off > 0; off >>= 1) {
        s1 += __shfl_xor(s1, off, 32);
        s2 += __shfl_xor(s2, off, 32);
    }
    float mu = s1 * (1.f / DD);
    float var = s2 * (1.f / DD) - mu * mu;
    float rstd = rsqrtf(var + LN_EPS);
    float alpha = alphas[layer];

    float4 w4 = *(const float4*)&lnw[f4];
    float4 lb4 = *(const float4*)&lnb[f4];
    float yx = (ax - mu) * rstd * w4.x + lb4.x;
    float yy = (ay - mu) * rstd * w4.y + lb4.y;
    float yz = (az - mu) * rstd * w4.z + lb4.z;
    float yw = (aw - mu) * rstd * w4.w + lb4.w;
    yx = (yx >= 0.f) ? yx : alpha * yx;
    yy = (yy >= 0.f) ? yy : alpha * yy;
    yz = (yz >= 0.f) ? yz : alpha * yz;
    yw = (yw >= 0.f) ? yw : alpha * yw;
    *(float4*)&out[(size_t)node * DD + f4] = make_float4(yx, yy, yz, yw);
}

// ---------------- launch ----------------

extern "C" void kernel_launch(void* const* d_in, const int* in_sizes, int n_in,
                              void* d_out, int out_size, void* d_ws, size_t ws_size,
                              hipStream_t stream) {
    const float* x    = (const float*)d_in[0];
    const int*   ei   = (const int*)d_in[1];
    const float* Ws   = (const float*)d_in[2];
    const float* bs   = (const float*)d_in[3];
    const float* lnw  = (const float*)d_in[4];
    const float* lnb  = (const float*)d_in[5];
    const float* alphas = (const float*)d_in[6];
    float* out = (float*)d_out;

    const int* src = ei;
    const int* dst = ei + EE;

    char* ws = (char*)d_ws;
    size_t off = 0;
    auto alloc = [&](size_t bytes) -> void* {
        void* p = ws + off;
        off = (off + bytes + 255) & ~(size_t)255;
        return p;
    };
    int*   deg      = (int*)alloc(NN * sizeof(int));
    float* dinv     = (float*)alloc(NN * sizeof(float));
    int*   rowoff   = (int*)alloc((NN + 1) * sizeof(int));
    int*   cursor   = (int*)alloc(NN * sizeof(int));
    int*   blocksum = (int*)alloc(SCAN_NB * sizeof(int));
    int*   blockpre = (int*)alloc(SCAN_NB * sizeof(int));
    int*   csrc     = (int*)alloc((size_t)(EE + NN) * sizeof(int));
    float* cnorm    = (float*)alloc((size_t)(EE + NN) * sizeof(float));
    float* tbuf     = (float*)alloc((size_t)NN * DD * sizeof(float));
    float* hbuf     = (float*)alloc((size_t)NN * DD * sizeof(float));

    hipMemsetAsync(deg, 0, NN * sizeof(int), stream);
    degree_kernel<<<(EE + 255) / 256, 256, 0, stream>>>(dst, deg);
    dinv_kernel<<<(NN + 255) / 256, 256, 0, stream>>>(deg, dinv);
    scan1_kernel<<<SCAN_NB, 256, 0, stream>>>(deg, blocksum);
    scan2_kernel<<<1, 256, 0, stream>>>(blocksum, blockpre, rowoff);
    scan3_kernel<<<SCAN_NB, 256, 0, stream>>>(deg, blockpre, rowoff);
    hipMemcpyAsync(cursor, rowoff, NN * sizeof(int), hipMemcpyDeviceToDevice, stream);
    fill_kernel<<<(EE + NN + 255) / 256, 256, 0, stream>>>(src, dst, dinv, cursor, csrc, cnorm);

    const int gemm_grid = (NN + BM - 1) / BM;
    for (int l = 0; l < LL; l++) {
        const float* A = (l == 0) ? x : hbuf;
        float* O = (l == LL - 1) ? out : hbuf;
        gemm_kernel<<<gemm_grid, 256, 0, stream>>>(A, Ws + (size_t)l * DD * DD, tbuf);
        agg_ln_kernel<<<(NN + 3) / 4, 128, 0, stream>>>(tbuf, rowoff, csrc, cnorm,
                                                        bs + l * DD, lnw + l * DD, lnb + l * DD,
                                                        alphas, l, O);
    }
}

// Round 3
// 342.989 us; speedup vs baseline: 1.6617x; 1.1762x over previous
//
#include <hip/hip_runtime.h>
#include <hip/hip_bf16.h>

#define NN 50000
#define EE 600000
#define DD 128
#define LL 3
#define LN_EPS 1e-5f

__device__ inline unsigned short f2bf(float f) {
    union { float f; unsigned u; } a; a.f = f;
    unsigned r = a.u + 0x7fffu + ((a.u >> 16) & 1u);  // RNE (finite values)
    return (unsigned short)(r >> 16);
}

// ---------------- CSR build ----------------

__global__ void degree_kernel(const int* __restrict__ dst, int* __restrict__ deg) {
    int i = blockIdx.x * blockDim.x + threadIdx.x;
    if (i < EE) atomicAdd(&deg[dst[i]], 1);
}

__global__ void dinv_kernel(const int* __restrict__ deg, float* __restrict__ dinv) {
    int i = blockIdx.x * blockDim.x + threadIdx.x;
    if (i < NN) dinv[i] = rsqrtf((float)(deg[i] + 1));  // +1 self-loop
}

#define SCAN_NB ((NN + 255) / 256)   // 196

__global__ __launch_bounds__(256) void scan1_kernel(const int* __restrict__ deg,
                                                    int* __restrict__ blocksum) {
    __shared__ int red[4];
    int i = blockIdx.x * 256 + threadIdx.x;
    int v = (i < NN) ? (deg[i] + 1) : 0;
    int s = v;
    #pragma unroll
    for (int off = 32; off > 0; off >>= 1) s += __shfl_down(s, off);
    if ((threadIdx.x & 63) == 0) red[threadIdx.x >> 6] = s;
    __syncthreads();
    if (threadIdx.x == 0) blocksum[blockIdx.x] = red[0] + red[1] + red[2] + red[3];
}

__global__ __launch_bounds__(256) void scan2_kernel(const int* __restrict__ blocksum,
                                                    int* __restrict__ blockpre,
                                                    int* __restrict__ rowoff) {
    __shared__ int s[256];
    int t = threadIdx.x;
    int v = (t < SCAN_NB) ? blocksum[t] : 0;
    s[t] = v;
    __syncthreads();
    #pragma unroll
    for (int off = 1; off < 256; off <<= 1) {
        int add = (t >= off) ? s[t - off] : 0;
        __syncthreads();
        s[t] += add;
        __syncthreads();
    }
    if (t < SCAN_NB) blockpre[t] = s[t] - v;
    if (t == 255) rowoff[NN] = s[255];
}

__global__ __launch_bounds__(256) void scan3_kernel(const int* __restrict__ deg,
                                                    const int* __restrict__ blockpre,
                                                    int* __restrict__ rowoff) {
    __shared__ int s[256];
    int t = threadIdx.x;
    int i = blockIdx.x * 256 + t;
    int v = (i < NN) ? (deg[i] + 1) : 0;
    s[t] = v;
    __syncthreads();
    #pragma unroll
    for (int off = 1; off < 256; off <<= 1) {
        int add = (t >= off) ? s[t - off] : 0;
        __syncthreads();
        s[t] += add;
        __syncthreads();
    }
    if (i < NN) rowoff[i] = blockpre[blockIdx.x] + s[t] - v;
}

// edge record: .x = src node, .y = float bits of norm weight
__global__ void fill_kernel(const int* __restrict__ src, const int* __restrict__ dst,
                            const float* __restrict__ dinv, int* __restrict__ cursor,
                            int2* __restrict__ ecsr) {
    int i = blockIdx.x * blockDim.x + threadIdx.x;
    if (i >= EE + NN) return;
    int s, d;
    if (i < EE) { s = src[i]; d = dst[i]; }
    else        { s = i - EE; d = s; }
    int pos = atomicAdd(&cursor[d], 1);
    float w = dinv[s] * dinv[d];
    ecsr[pos] = make_int2(s, __float_as_int(w));
}

// ---------------- GEMM: C[N,128] = A[N,128] @ W[128,128], bf16 out ----------

#define BM 64
#define BN 128
#define BK 16

__global__ __launch_bounds__(256) void gemm_kernel(const float* __restrict__ A,
                                                   const float* __restrict__ W,
                                                   unsigned short* __restrict__ Cb) {
    __shared__ float As[BK][BM + 4];
    __shared__ float Bs[BK][BN + 4];
    int tid = threadIdx.x;
    int tx = tid & 15;    // 8 cols each
    int ty = tid >> 4;    // 4 rows each
    int rowbase = blockIdx.x * BM;
    float acc[4][8] = {};

    for (int k0 = 0; k0 < DD; k0 += BK) {
        {
            int r = tid >> 2;
            int kq = (tid & 3) * 4;
            int grow = rowbase + r;
            float4 av = make_float4(0.f, 0.f, 0.f, 0.f);
            if (grow < NN) av = *(const float4*)&A[(size_t)grow * DD + k0 + kq];
            As[kq + 0][r] = av.x; As[kq + 1][r] = av.y;
            As[kq + 2][r] = av.z; As[kq + 3][r] = av.w;
        }
        {
            int kk = tid >> 4;
            int col = (tid & 15) * 8;
            const float* wp = &W[(k0 + kk) * DD + col];
            *(float4*)&Bs[kk][col]     = *(const float4*)&wp[0];
            *(float4*)&Bs[kk][col + 4] = *(const float4*)&wp[4];
        }
        __syncthreads();
        #pragma unroll
        for (int kk = 0; kk < BK; kk++) {
            float4 a  = *(const float4*)&As[kk][ty * 4];
            float4 b0 = *(const float4*)&Bs[kk][tx * 8];
            float4 b1 = *(const float4*)&Bs[kk][tx * 8 + 4];
            float av[4] = {a.x, a.y, a.z, a.w};
            float bv[8] = {b0.x, b0.y, b0.z, b0.w, b1.x, b1.y, b1.z, b1.w};
            #pragma unroll
            for (int i = 0; i < 4; i++)
                #pragma unroll
                for (int j = 0; j < 8; j++)
                    acc[i][j] += av[i] * bv[j];
        }
        __syncthreads();
    }
    #pragma unroll
    for (int i = 0; i < 4; i++) {
        int grow = rowbase + ty * 4 + i;
        if (grow < NN) {
            union { unsigned short u[8]; float4 v; } pk;
            #pragma unroll
            for (int j = 0; j < 8; j++) pk.u[j] = f2bf(acc[i][j]);
            *(float4*)&Cb[(size_t)grow * DD + tx * 8] = pk.v;
        }
    }
}

// ---------------- fused aggregate + bias + LayerNorm + PReLU ----------------
// 128 threads = 8 groups of 16 lanes; group g handles node blockIdx*8+g.
// Lane l owns features [8l, 8l+8): one dwordx4 (8 bf16) per edge row.

__global__ __launch_bounds__(128) void agg_ln_kernel(
    const unsigned short* __restrict__ Tb, const int* __restrict__ rowoff,
    const int2* __restrict__ ecsr,
    const float* __restrict__ bias, const float* __restrict__ lnw,
    const float* __restrict__ lnb, const float* __restrict__ alphas, int layer,
    float* __restrict__ out) {
    int g = threadIdx.x >> 4;
    int lane = threadIdx.x & 15;
    int node = blockIdx.x * 8 + g;
    if (node >= NN) return;
    int start = rowoff[node];
    int end = rowoff[node + 1];
    int f8 = lane * 8;

    float acc[8] = {};
    for (int e = start; e < end; e++) {
        int2 ev = ecsr[e];
        float w = __int_as_float(ev.y);
        uint4 t = *(const uint4*)&Tb[(size_t)ev.x * DD + f8];
        unsigned uu[4] = {t.x, t.y, t.z, t.w};
        #pragma unroll
        for (int q = 0; q < 4; q++) {
            union { unsigned x; float f; } lo, hi;
            lo.x = uu[q] << 16;
            hi.x = uu[q] & 0xffff0000u;
            acc[2 * q]     += w * lo.f;
            acc[2 * q + 1] += w * hi.f;
        }
    }
    float4 b0 = *(const float4*)&bias[f8];
    float4 b1 = *(const float4*)&bias[f8 + 4];
    acc[0] += b0.x; acc[1] += b0.y; acc[2] += b0.z; acc[3] += b0.w;
    acc[4] += b1.x; acc[5] += b1.y; acc[6] += b1.z; acc[7] += b1.w;

    float s1 = 0.f, s2 = 0.f;
    #pragma unroll
    for (int q = 0; q < 8; q++) { s1 += acc[q]; s2 += acc[q] * acc[q]; }
    #pragma unroll
    for (int off = 8; off > 0; off >>= 1) {
        s1 += __shfl_xor(s1, off, 16);
        s2 += __shfl_xor(s2, off, 16);
    }
    float mu = s1 * (1.f / DD);
    float var = s2 * (1.f / DD) - mu * mu;
    float rstd = rsqrtf(var + LN_EPS);
    float alpha = alphas[layer];

    float4 w0 = *(const float4*)&lnw[f8];
    float4 w1 = *(const float4*)&lnw[f8 + 4];
    float4 c0 = *(const float4*)&lnb[f8];
    float4 c1 = *(const float4*)&lnb[f8 + 4];
    float wv[8] = {w0.x, w0.y, w0.z, w0.w, w1.x, w1.y, w1.z, w1.w};
    float cv[8] = {c0.x, c0.y, c0.z, c0.w, c1.x, c1.y, c1.z, c1.w};
    float yv[8];
    #pragma unroll
    for (int q = 0; q < 8; q++) {
        float y = (acc[q] - mu) * rstd * wv[q] + cv[q];
        yv[q] = (y >= 0.f) ? y : alpha * y;
    }
    float* op = &out[(size_t)node * DD + f8];
    *(float4*)&op[0] = make_float4(yv[0], yv[1], yv[2], yv[3]);
    *(float4*)&op[4] = make_float4(yv[4], yv[5], yv[6], yv[7]);
}

// ---------------- launch ----------------

extern "C" void kernel_launch(void* const* d_in, const int* in_sizes, int n_in,
                              void* d_out, int out_size, void* d_ws, size_t ws_size,
                              hipStream_t stream) {
    const float* x    = (const float*)d_in[0];
    const int*   ei   = (const int*)d_in[1];
    const float* Ws   = (const float*)d_in[2];
    const float* bs   = (const float*)d_in[3];
    const float* lnw  = (const float*)d_in[4];
    const float* lnb  = (const float*)d_in[5];
    const float* alphas = (const float*)d_in[6];
    float* out = (float*)d_out;

    const int* src = ei;
    const int* dst = ei + EE;

    char* ws = (char*)d_ws;
    size_t off = 0;
    auto alloc = [&](size_t bytes) -> void* {
        void* p = ws + off;
        off = (off + bytes + 255) & ~(size_t)255;
        return p;
    };
    int*   deg      = (int*)alloc(NN * sizeof(int));
    float* dinv     = (float*)alloc(NN * sizeof(float));
    int*   rowoff   = (int*)alloc((NN + 1) * sizeof(int));
    int*   cursor   = (int*)alloc(NN * sizeof(int));
    int*   blocksum = (int*)alloc(SCAN_NB * sizeof(int));
    int*   blockpre = (int*)alloc(SCAN_NB * sizeof(int));
    int2*  ecsr     = (int2*)alloc((size_t)(EE + NN) * sizeof(int2));
    unsigned short* tbuf = (unsigned short*)alloc((size_t)NN * DD * sizeof(unsigned short));
    float* hbuf     = (float*)alloc((size_t)NN * DD * sizeof(float));

    hipMemsetAsync(deg, 0, NN * sizeof(int), stream);
    degree_kernel<<<(EE + 255) / 256, 256, 0, stream>>>(dst, deg);
    dinv_kernel<<<(NN + 255) / 256, 256, 0, stream>>>(deg, dinv);
    scan1_kernel<<<SCAN_NB, 256, 0, stream>>>(deg, blocksum);
    scan2_kernel<<<1, 256, 0, stream>>>(blocksum, blockpre, rowoff);
    scan3_kernel<<<SCAN_NB, 256, 0, stream>>>(deg, blockpre, rowoff);
    hipMemcpyAsync(cursor, rowoff, NN * sizeof(int), hipMemcpyDeviceToDevice, stream);
    fill_kernel<<<(EE + NN + 255) / 256, 256, 0, stream>>>(src, dst, dinv, cursor, ecsr);

    const int gemm_grid = (NN + BM - 1) / BM;
    for (int l = 0; l < LL; l++) {
        const float* A = (l == 0) ? x : hbuf;
        float* O = (l == LL - 1) ? out : hbuf;
        gemm_kernel<<<gemm_grid, 256, 0, stream>>>(A, Ws + (size_t)l * DD * DD, tbuf);
        agg_ln_kernel<<<(NN + 7) / 8, 128, 0, stream>>>(tbuf, rowoff, ecsr,
                                                        bs + l * DD, lnw + l * DD, lnb + l * DD,
                                                        alphas, l, O);
    }
}

// Round 4
// 311.272 us; speedup vs baseline: 1.8310x; 1.1019x over previous
//
#include <hip/hip_runtime.h>
#include <hip/hip_bf16.h>

#define NN 50000
#define EE 600000
#define DD 128
#define LL 3
#define LN_EPS 1e-5f

typedef __attribute__((ext_vector_type(8))) short short8;
typedef __attribute__((ext_vector_type(4))) float floatx4;

__device__ inline unsigned short f2bf(float f) {
    union { float f; unsigned u; } a; a.f = f;
    unsigned r = a.u + 0x7fffu + ((a.u >> 16) & 1u);  // RNE (finite values)
    return (unsigned short)(r >> 16);
}

// ---------------- CSR build ----------------

__global__ void degree_kernel(const int* __restrict__ dst, int* __restrict__ deg) {
    int i = blockIdx.x * blockDim.x + threadIdx.x;
    if (i < EE) atomicAdd(&deg[dst[i]], 1);
}

#define SCAN_NB ((NN + 255) / 256)   // 196

// blocksum + dinv fused
__global__ __launch_bounds__(256) void scan1_kernel(const int* __restrict__ deg,
                                                    int* __restrict__ blocksum,
                                                    float* __restrict__ dinv) {
    __shared__ int red[4];
    int i = blockIdx.x * 256 + threadIdx.x;
    int d = (i < NN) ? (deg[i] + 1) : 0;
    if (i < NN) dinv[i] = rsqrtf((float)d);
    int s = d;
    #pragma unroll
    for (int off = 32; off > 0; off >>= 1) s += __shfl_down(s, off);
    if ((threadIdx.x & 63) == 0) red[threadIdx.x >> 6] = s;
    __syncthreads();
    if (threadIdx.x == 0) blocksum[blockIdx.x] = red[0] + red[1] + red[2] + red[3];
}

__global__ __launch_bounds__(256) void scan2_kernel(const int* __restrict__ blocksum,
                                                    int* __restrict__ blockpre,
                                                    int* __restrict__ rowoff) {
    __shared__ int s[256];
    int t = threadIdx.x;
    int v = (t < SCAN_NB) ? blocksum[t] : 0;
    s[t] = v;
    __syncthreads();
    #pragma unroll
    for (int off = 1; off < 256; off <<= 1) {
        int add = (t >= off) ? s[t - off] : 0;
        __syncthreads();
        s[t] += add;
        __syncthreads();
    }
    if (t < SCAN_NB) blockpre[t] = s[t] - v;
    if (t == 255) rowoff[NN] = s[255];
}

// rowoff + cursor fused
__global__ __launch_bounds__(256) void scan3_kernel(const int* __restrict__ deg,
                                                    const int* __restrict__ blockpre,
                                                    int* __restrict__ rowoff,
                                                    int* __restrict__ cursor) {
    __shared__ int s[256];
    int t = threadIdx.x;
    int i = blockIdx.x * 256 + t;
    int v = (i < NN) ? (deg[i] + 1) : 0;
    s[t] = v;
    __syncthreads();
    #pragma unroll
    for (int off = 1; off < 256; off <<= 1) {
        int add = (t >= off) ? s[t - off] : 0;
        __syncthreads();
        s[t] += add;
        __syncthreads();
    }
    if (i < NN) {
        int r = blockpre[blockIdx.x] + s[t] - v;
        rowoff[i] = r;
        cursor[i] = r;
    }
}

// edge record: .x = src node, .y = float bits of norm weight
__global__ void fill_kernel(const int* __restrict__ src, const int* __restrict__ dst,
                            const float* __restrict__ dinv, int* __restrict__ cursor,
                            int2* __restrict__ ecsr) {
    int i = blockIdx.x * blockDim.x + threadIdx.x;
    if (i >= EE + NN) return;
    int s, d;
    if (i < EE) { s = src[i]; d = dst[i]; }
    else        { s = i - EE; d = s; }
    int pos = atomicAdd(&cursor[d], 1);
    float w = dinv[s] * dinv[d];
    ecsr[pos] = make_int2(s, __float_as_int(w));
}

// ---------------- W transpose to bf16: Wt[l][n][k] = bf16(W[l][k][n]) --------

__global__ void wt_kernel(const float* __restrict__ W, unsigned short* __restrict__ Wt) {
    int i = blockIdx.x * blockDim.x + threadIdx.x;   // l*16384 + n*128 + k
    if (i >= LL * DD * DD) return;
    int l = i >> 14;
    int n = (i >> 7) & 127;
    int k = i & 127;
    Wt[i] = f2bf(W[(l << 14) + k * DD + n]);
}

// ---------------- MFMA GEMM: C[N,128] = A[N,128] @ W[128,128], bf16 out -----
// 32 rows/block, 256 threads = 4 waves. Wave w: rows (w>>1)*16, cols (w&1)*64.
// B-frags (W^T) in registers; A staged in LDS (pad 8 shorts -> 2-way = free).

#define ALD 136   // padded row stride in shorts

template <typename AT>
__global__ __launch_bounds__(256) void gemm_mfma(const AT* __restrict__ A,
                                                 const unsigned short* __restrict__ Wt,
                                                 unsigned short* __restrict__ Cb) {
    __shared__ unsigned short alds[32 * ALD];
    int tid = threadIdx.x;
    int lane = tid & 63;
    int w = tid >> 6;
    int rowbase = blockIdx.x * 32;

    // B fragments: bfr[n-tile j][k-tile t]
    int cbase = (w & 1) * 64;
    int nIdx = cbase + (lane & 15);
    int kq = (lane >> 4) * 8;
    short8 bfr[4][4];
    #pragma unroll
    for (int j = 0; j < 4; j++)
        #pragma unroll
        for (int t = 0; t < 4; t++)
            bfr[j][t] = *(const short8*)&Wt[(nIdx + j * 16) * DD + t * 32 + kq];

    // stage A tile: thread t -> local row t>>3, k range (t&7)*16..+16
    {
        int r = tid >> 3;
        int k0 = (tid & 7) * 16;
        int grow = rowbase + r;
        unsigned short* dstp = &alds[r * ALD + k0];
        if (grow < NN) {
            const AT* ap = &A[(size_t)grow * DD + k0];
            if constexpr (sizeof(AT) == 4) {   // f32 input: convert
                float4 v0 = *(const float4*)&ap[0];
                float4 v1 = *(const float4*)&ap[4];
                float4 v2 = *(const float4*)&ap[8];
                float4 v3 = *(const float4*)&ap[12];
                float fv[16] = {v0.x,v0.y,v0.z,v0.w, v1.x,v1.y,v1.z,v1.w,
                                v2.x,v2.y,v2.z,v2.w, v3.x,v3.y,v3.z,v3.w};
                unsigned short uv[16];
                #pragma unroll
                for (int q = 0; q < 16; q++) uv[q] = f2bf(fv[q]);
                *(uint4*)&dstp[0] = *(uint4*)&uv[0];
                *(uint4*)&dstp[8] = *(uint4*)&uv[8];
            } else {                            // bf16 input: copy
                *(uint4*)&dstp[0] = *(const uint4*)&ap[0];
                *(uint4*)&dstp[8] = *(const uint4*)&ap[8];
            }
        } else {
            uint4 z = make_uint4(0, 0, 0, 0);
            *(uint4*)&dstp[0] = z;
            *(uint4*)&dstp[8] = z;
        }
    }
    __syncthreads();

    int rbase = (w >> 1) * 16;
    int mrow = rbase + (lane & 15);
    floatx4 acc[4] = {{0.f,0.f,0.f,0.f},{0.f,0.f,0.f,0.f},
                      {0.f,0.f,0.f,0.f},{0.f,0.f,0.f,0.f}};
    #pragma unroll
    for (int t = 0; t < 4; t++) {
        short8 a = *(const short8*)&alds[mrow * ALD + t * 32 + kq];
        #pragma unroll
        for (int j = 0; j < 4; j++)
            acc[j] = __builtin_amdgcn_mfma_f32_16x16x32_bf16(a, bfr[j][t], acc[j], 0, 0, 0);
    }

    // C layout: row = (lane>>4)*4 + i, col = j*16 + (lane&15)
    int gnode0 = rowbase + rbase + (lane >> 4) * 4;
    #pragma unroll
    for (int i = 0; i < 4; i++) {
        int node = gnode0 + i;
        if (node < NN) {
            #pragma unroll
            for (int j = 0; j < 4; j++)
                Cb[(size_t)node * DD + cbase + j * 16 + (lane & 15)] = f2bf(acc[j][i]);
        }
    }
}

// ---------------- fused aggregate + bias + LayerNorm + PReLU ----------------
// 128 threads = 8 groups of 16 lanes; group g handles node blockIdx*8+g.
// Lane l owns features [8l, 8l+8): one dwordx4 (8 bf16) per edge row.
// OUT = unsigned short (bf16 hbuf) or float (final d_out).

template <typename OUT>
__global__ __launch_bounds__(128) void agg_ln_kernel(
    const unsigned short* __restrict__ Tb, const int* __restrict__ rowoff,
    const int2* __restrict__ ecsr,
    const float* __restrict__ bias, const float* __restrict__ lnw,
    const float* __restrict__ lnb, const float* __restrict__ alphas, int layer,
    OUT* __restrict__ out) {
    int g = threadIdx.x >> 4;
    int lane = threadIdx.x & 15;
    int node = blockIdx.x * 8 + g;
    if (node >= NN) return;
    int start = rowoff[node];
    int end = rowoff[node + 1];
    int f8 = lane * 8;

    float acc[8] = {};
    for (int e = start; e < end; e++) {
        int2 ev = ecsr[e];
        float w = __int_as_float(ev.y);
        uint4 t = *(const uint4*)&Tb[(size_t)ev.x * DD + f8];
        unsigned uu[4] = {t.x, t.y, t.z, t.w};
        #pragma unroll
        for (int q = 0; q < 4; q++) {
            union { unsigned x; float f; } lo, hi;
            lo.x = uu[q] << 16;
            hi.x = uu[q] & 0xffff0000u;
            acc[2 * q]     += w * lo.f;
            acc[2 * q + 1] += w * hi.f;
        }
    }
    float4 b0 = *(const float4*)&bias[f8];
    float4 b1 = *(const float4*)&bias[f8 + 4];
    acc[0] += b0.x; acc[1] += b0.y; acc[2] += b0.z; acc[3] += b0.w;
    acc[4] += b1.x; acc[5] += b1.y; acc[6] += b1.z; acc[7] += b1.w;

    float s1 = 0.f, s2 = 0.f;
    #pragma unroll
    for (int q = 0; q < 8; q++) { s1 += acc[q]; s2 += acc[q] * acc[q]; }
    #pragma unroll
    for (int off = 8; off > 0; off >>= 1) {
        s1 += __shfl_xor(s1, off, 16);
        s2 += __shfl_xor(s2, off, 16);
    }
    float mu = s1 * (1.f / DD);
    float var = s2 * (1.f / DD) - mu * mu;
    float rstd = rsqrtf(var + LN_EPS);
    float alpha = alphas[layer];

    float4 w0 = *(const float4*)&lnw[f8];
    float4 w1 = *(const float4*)&lnw[f8 + 4];
    float4 c0 = *(const float4*)&lnb[f8];
    float4 c1 = *(const float4*)&lnb[f8 + 4];
    float wv[8] = {w0.x, w0.y, w0.z, w0.w, w1.x, w1.y, w1.z, w1.w};
    float cv[8] = {c0.x, c0.y, c0.z, c0.w, c1.x, c1.y, c1.z, c1.w};
    float yv[8];
    #pragma unroll
    for (int q = 0; q < 8; q++) {
        float y = (acc[q] - mu) * rstd * wv[q] + cv[q];
        yv[q] = (y >= 0.f) ? y : alpha * y;
    }
    if constexpr (sizeof(OUT) == 2) {
        unsigned short pv[8];
        #pragma unroll
        for (int q = 0; q < 8; q++) pv[q] = f2bf(yv[q]);
        *(uint4*)&out[(size_t)node * DD + f8] = *(uint4*)&pv[0];
    } else {
        float* op = (float*)&out[(size_t)node * DD + f8];
        *(float4*)&op[0] = make_float4(yv[0], yv[1], yv[2], yv[3]);
        *(float4*)&op[4] = make_float4(yv[4], yv[5], yv[6], yv[7]);
    }
}

// ---------------- launch ----------------

extern "C" void kernel_launch(void* const* d_in, const int* in_sizes, int n_in,
                              void* d_out, int out_size, void* d_ws, size_t ws_size,
                              hipStream_t stream) {
    const float* x    = (const float*)d_in[0];
    const int*   ei   = (const int*)d_in[1];
    const float* Ws   = (const float*)d_in[2];
    const float* bs   = (const float*)d_in[3];
    const float* lnw  = (const float*)d_in[4];
    const float* lnb  = (const float*)d_in[5];
    const float* alphas = (const float*)d_in[6];
    float* out = (float*)d_out;

    const int* src = ei;
    const int* dst = ei + EE;

    char* ws = (char*)d_ws;
    size_t off = 0;
    auto alloc = [&](size_t bytes) -> void* {
        void* p = ws + off;
        off = (off + bytes + 255) & ~(size_t)255;
        return p;
    };
    int*   deg      = (int*)alloc(NN * sizeof(int));
    float* dinv     = (float*)alloc(NN * sizeof(float));
    int*   rowoff   = (int*)alloc((NN + 1) * sizeof(int));
    int*   cursor   = (int*)alloc(NN * sizeof(int));
    int*   blocksum = (int*)alloc(SCAN_NB * sizeof(int));
    int*   blockpre = (int*)alloc(SCAN_NB * sizeof(int));
    int2*  ecsr     = (int2*)alloc((size_t)(EE + NN) * sizeof(int2));
    unsigned short* wt   = (unsigned short*)alloc((size_t)LL * DD * DD * sizeof(unsigned short));
    unsigned short* tbuf = (unsigned short*)alloc((size_t)NN * DD * sizeof(unsigned short));
    unsigned short* hbuf = (unsigned short*)alloc((size_t)NN * DD * sizeof(unsigned short));

    hipMemsetAsync(deg, 0, NN * sizeof(int), stream);
    degree_kernel<<<(EE + 255) / 256, 256, 0, stream>>>(dst, deg);
    scan1_kernel<<<SCAN_NB, 256, 0, stream>>>(deg, blocksum, dinv);
    scan2_kernel<<<1, 256, 0, stream>>>(blocksum, blockpre, rowoff);
    scan3_kernel<<<SCAN_NB, 256, 0, stream>>>(deg, blockpre, rowoff, cursor);
    fill_kernel<<<(EE + NN + 255) / 256, 256, 0, stream>>>(src, dst, dinv, cursor, ecsr);
    wt_kernel<<<(LL * DD * DD + 255) / 256, 256, 0, stream>>>(Ws, wt);

    const int gemm_grid = (NN + 31) / 32;
    const int agg_grid = (NN + 7) / 8;
    for (int l = 0; l < LL; l++) {
        const unsigned short* wl = wt + (size_t)l * DD * DD;
        if (l == 0)
            gemm_mfma<float><<<gemm_grid, 256, 0, stream>>>(x, wl, tbuf);
        else
            gemm_mfma<unsigned short><<<gemm_grid, 256, 0, stream>>>(hbuf, wl, tbuf);
        if (l == LL - 1)
            agg_ln_kernel<float><<<agg_grid, 128, 0, stream>>>(
                tbuf, rowoff, ecsr, bs + l * DD, lnw + l * DD, lnb + l * DD, alphas, l, out);
        else
            agg_ln_kernel<unsigned short><<<agg_grid, 128, 0, stream>>>(
                tbuf, rowoff, ecsr, bs + l * DD, lnw + l * DD, lnb + l * DD, alphas, l, hbuf);
    }
}